// Round 2
// baseline (470.135 us; speedup 1.0000x reference)
//
#include <hip/hip_runtime.h>

#define LL 32
#define HH 64

// Broadcast lane `lane`'s value of v to all lanes via v_readlane (VALU, no LDS pipe).
__device__ __forceinline__ float bcast_lane(float v, int lane) {
  return __builtin_bit_cast(float, __builtin_amdgcn_readlane(__builtin_bit_cast(int, v), lane));
}

// One DPP-shifted add step (bound_ctrl: out-of-range lanes contribute 0).
// CTRL must be a compile-time constant for __builtin_amdgcn_update_dpp.
template <int CTRL>
__device__ __forceinline__ float dpp_add_step(float x) {
  int y = __builtin_amdgcn_update_dpp(0, __builtin_bit_cast(int, x), CTRL, 0xf, 0xf, true);
  return x + __builtin_bit_cast(float, y);
}

// Full 64-lane sum, result broadcast as a wave-uniform value (via readlane 63).
// row_shr:1/2/4/8 accumulate within 16-lane rows; row_bcast15/31 merge rows.
__device__ __forceinline__ float wave_sum64(float x) {
  x = dpp_add_step<0x111>(x);  // row_shr:1
  x = dpp_add_step<0x112>(x);  // row_shr:2
  x = dpp_add_step<0x114>(x);  // row_shr:4
  x = dpp_add_step<0x118>(x);  // row_shr:8
  x = dpp_add_step<0x142>(x);  // row_bcast15
  x = dpp_add_step<0x143>(x);  // row_bcast31
  return __builtin_bit_cast(float, __builtin_amdgcn_readlane(__builtin_bit_cast(int, x), 63));
}

// One wave (64 lanes) per sample. Lane j owns hidden unit j.
// Wc column j in 64 VGPRs; vertical hidden carry prevH[c][j] in LDS (per-lane column).
__global__ __launch_bounds__(64) void rnn2d_kernel(
    const int* __restrict__ x, const float* __restrict__ Win,
    const float* __restrict__ Wc, const float* __restrict__ bc,
    const float* __restrict__ Wout, const float* __restrict__ bout,
    float* __restrict__ out) {
  const int lane = threadIdx.x;
  const int b = blockIdx.x;
  __shared__ float vrow[LL * HH];  // [column][hidden] — lane j only touches [.][j]

  // Weights resident in registers for the whole 1024-step recurrence.
  float wcol[HH];
#pragma unroll
  for (int i = 0; i < HH; ++i) wcol[i] = Wc[i * HH + lane];
  const float win0 = Win[lane];            // Win[0][j]
  const float win1 = Win[HH + lane];       // Win[1][j]
  const float bcj = bc[lane];
  const float wout0 = Wout[lane * 2 + 0];  // Wout[j][0]
  const float wout1 = Wout[lane * 2 + 1];  // Wout[j][1]
  const float bout0 = bout[0];
  const float bout1 = bout[1];

  // Row 0 sees zero vertical hidden carry.
#pragma unroll
  for (int c0 = 0; c0 < LL; ++c0) vrow[c0 * HH + lane] = 0.f;

  const int* xb = x + b * (LL * LL);
  unsigned prevmask = 0u;                         // previous row's spins (bit c = spin at column c)
  int spv = (lane < LL) ? xb[lane] : 0;           // prefetched row-0 spins
  float total = 0.f;

  for (int r = 0; r < LL; ++r) {
    const unsigned curmask =
        (unsigned)(__ballot(lane < LL && spv) & 0xffffffffull);
    if (r < LL - 1) spv = (lane < LL) ? xb[(r + 1) * LL + lane] : 0;  // prefetch next row

    const int odd = r & 1;
    const int d = odd ? -1 : 1;       // boustrophedon direction
    int c = odd ? (LL - 1) : 0;       // spatial column of scan step 0
    float hcur = 0.f;                 // horizontal hidden carry (zero at row start)
    float vj = vrow[c * HH + lane];   // vertical carry for step 0

    for (int k = 0; k < LL; ++k) {
      // Prefetch next step's vertical carry (address is ahead of this row's writes).
      const int cn = (c + d) & (LL - 1);
      const float vj_next = vrow[cn * HH + lane];

      const float hv = hcur + vj;  // (h + cV)[j], to be broadcast across lanes

      // newH[j] = sum_i hv[i] * Wc[i][j] — readlane broadcast + FMA, 4 accumulators.
      float a0 = 0.f, a1 = 0.f, a2 = 0.f, a3 = 0.f;
#pragma unroll
      for (int i = 0; i < HH; i += 4) {
        a0 = fmaf(bcast_lane(hv, i + 0), wcol[i + 0], a0);
        a1 = fmaf(bcast_lane(hv, i + 1), wcol[i + 1], a1);
        a2 = fmaf(bcast_lane(hv, i + 2), wcol[i + 2], a2);
        a3 = fmaf(bcast_lane(hv, i + 3), wcol[i + 3], a3);
      }

      // newR @ Win: one-hot row selects (spins are wave-uniform scalars from the bitmasks).
      float winc = 0.f;
      if (k > 0) {  // horizontal neighbor (previously visited site in this row)
        const unsigned sh = (curmask >> ((c - d) & 31)) & 1u;
        winc += sh ? win1 : win0;
      }
      if (r > 0) {  // vertical neighbor (same column, previous row)
        const unsigned sv = (prevmask >> c) & 1u;
        winc += sv ? win1 : win0;
      }

      const float pre = ((a0 + a1) + (a2 + a3)) + bcj + winc;
      // elu: x>0 ? x : exp(x)-1  (exp computed branchlessly; inf on big +x is discarded)
      const float hnew = pre > 0.f ? pre : (__expf(pre) - 1.f);

      vrow[c * HH + lane] = hnew;  // vertical carry for next row
      hcur = hnew;

      // log_softmax(newH @ Wout + bout), pick logit of actual spin; off critical path.
      const float z0 = wave_sum64(hnew * wout0) + bout0;
      const float z1 = wave_sum64(hnew * wout1) + bout1;
      const float m = fmaxf(z0, z1);
      const float lse = m + __logf(__expf(z0 - m) + __expf(z1 - m));
      const unsigned spin = (curmask >> c) & 1u;
      float lp = (spin ? z1 : z0) - lse;
      lp = (lp == lp) ? lp : -35.0f;  // nan_to_num(nan=-35)
      total += lp;

      vj = vj_next;
      c = cn;
    }
    prevmask = curmask;
  }

  if (lane == 0) out[b] = 0.5f * total;  // LOGP_FACTOR * sum
}

extern "C" void kernel_launch(void* const* d_in, const int* in_sizes, int n_in,
                              void* d_out, int out_size, void* d_ws, size_t ws_size,
                              hipStream_t stream) {
  const int* x = (const int*)d_in[0];
  const float* Win = (const float*)d_in[1];
  const float* Wc = (const float*)d_in[2];
  const float* bc = (const float*)d_in[3];
  const float* Wout = (const float*)d_in[4];
  const float* bout = (const float*)d_in[5];
  float* out = (float*)d_out;
  // One 64-thread block (one wave) per batch sample.
  rnn2d_kernel<<<dim3(out_size), dim3(64), 0, stream>>>(x, Win, Wc, bc, Wout, bout, out);
}

// Round 3
// 468.728 us; speedup vs baseline: 1.0030x; 1.0030x over previous
//
#include <hip/hip_runtime.h>

#define LL 32
#define HH 64

// Broadcast lane `lane`'s value of v to all lanes via v_readlane (VALU, no LDS pipe).
__device__ __forceinline__ float bcast_lane(float v, int lane) {
  return __builtin_bit_cast(float, __builtin_amdgcn_readlane(__builtin_bit_cast(int, v), lane));
}

// One DPP-shifted add step (bound_ctrl: out-of-range lanes contribute 0).
// CTRL must be a compile-time constant for __builtin_amdgcn_update_dpp.
template <int CTRL>
__device__ __forceinline__ float dpp_add_step(float x) {
  int y = __builtin_amdgcn_update_dpp(0, __builtin_bit_cast(int, x), CTRL, 0xf, 0xf, true);
  return x + __builtin_bit_cast(float, y);
}

// Full 64-lane sum, result broadcast as a wave-uniform value (via readlane 63).
// row_shr:1/2/4/8 accumulate within 16-lane rows; row_bcast15/31 merge rows.
__device__ __forceinline__ float wave_sum64(float x) {
  x = dpp_add_step<0x111>(x);  // row_shr:1
  x = dpp_add_step<0x112>(x);  // row_shr:2
  x = dpp_add_step<0x114>(x);  // row_shr:4
  x = dpp_add_step<0x118>(x);  // row_shr:8
  x = dpp_add_step<0x142>(x);  // row_bcast15
  x = dpp_add_step<0x143>(x);  // row_bcast31
  return __builtin_bit_cast(float, __builtin_amdgcn_readlane(__builtin_bit_cast(int, x), 63));
}

// One wave (64 lanes) per sample. Lane j owns hidden unit j.
// Wc column j in 64 VGPRs; vertical hidden carry prevH[c][j] in LDS (per-lane column).
// __launch_bounds__(64, 1): 1 wave/EU is the structural occupancy (1024 waves on
// 1024 SIMDs) — allow the register allocator the full VGPR file so wcol[64]
// stays resident for all 1024 steps (at default bounds the compiler capped at
// 44 VGPRs and re-loaded Wc every step: ~1015 cyc/step instead of ~400).
__global__ __launch_bounds__(64, 1) void rnn2d_kernel(
    const int* __restrict__ x, const float* __restrict__ Win,
    const float* __restrict__ Wc, const float* __restrict__ bc,
    const float* __restrict__ Wout, const float* __restrict__ bout,
    float* __restrict__ out) {
  const int lane = threadIdx.x;
  const int b = blockIdx.x;
  __shared__ float vrow[LL * HH];  // [column][hidden] — lane j only touches [.][j]

  // Weights resident in registers for the whole 1024-step recurrence.
  float wcol[HH];
#pragma unroll
  for (int i = 0; i < HH; ++i) wcol[i] = Wc[i * HH + lane];
  const float win0 = Win[lane];            // Win[0][j]
  const float win1 = Win[HH + lane];       // Win[1][j]
  const float bcj = bc[lane];
  const float wout0 = Wout[lane * 2 + 0];  // Wout[j][0]
  const float wout1 = Wout[lane * 2 + 1];  // Wout[j][1]
  const float bout0 = bout[0];
  const float bout1 = bout[1];

  // Row 0 sees zero vertical hidden carry.
#pragma unroll
  for (int c0 = 0; c0 < LL; ++c0) vrow[c0 * HH + lane] = 0.f;

  const int* xb = x + b * (LL * LL);
  unsigned prevmask = 0u;                         // previous row's spins (bit c = spin at column c)
  int spv = (lane < LL) ? xb[lane] : 0;           // prefetched row-0 spins
  float total = 0.f;

  for (int r = 0; r < LL; ++r) {
    const unsigned curmask =
        (unsigned)(__ballot(lane < LL && spv) & 0xffffffffull);
    if (r < LL - 1) spv = (lane < LL) ? xb[(r + 1) * LL + lane] : 0;  // prefetch next row

    const int odd = r & 1;
    const int d = odd ? -1 : 1;       // boustrophedon direction
    int c = odd ? (LL - 1) : 0;       // spatial column of scan step 0
    float hcur = 0.f;                 // horizontal hidden carry (zero at row start)
    float vj = vrow[c * HH + lane];   // vertical carry for step 0

    for (int k = 0; k < LL; ++k) {
      // Prefetch next step's vertical carry (address is ahead of this row's writes).
      const int cn = (c + d) & (LL - 1);
      const float vj_next = vrow[cn * HH + lane];

      const float hv = hcur + vj;  // (h + cV)[j], to be broadcast across lanes

      // newH[j] = sum_i hv[i] * Wc[i][j] — readlane broadcast + FMA, 4 accumulators.
      float a0 = 0.f, a1 = 0.f, a2 = 0.f, a3 = 0.f;
#pragma unroll
      for (int i = 0; i < HH; i += 4) {
        a0 = fmaf(bcast_lane(hv, i + 0), wcol[i + 0], a0);
        a1 = fmaf(bcast_lane(hv, i + 1), wcol[i + 1], a1);
        a2 = fmaf(bcast_lane(hv, i + 2), wcol[i + 2], a2);
        a3 = fmaf(bcast_lane(hv, i + 3), wcol[i + 3], a3);
      }

      // newR @ Win: one-hot row selects (spins are wave-uniform scalars from the bitmasks).
      float winc = 0.f;
      if (k > 0) {  // horizontal neighbor (previously visited site in this row)
        const unsigned sh = (curmask >> ((c - d) & 31)) & 1u;
        winc += sh ? win1 : win0;
      }
      if (r > 0) {  // vertical neighbor (same column, previous row)
        const unsigned sv = (prevmask >> c) & 1u;
        winc += sv ? win1 : win0;
      }

      const float pre = ((a0 + a1) + (a2 + a3)) + bcj + winc;
      // elu: x>0 ? x : exp(x)-1  (exp computed branchlessly; inf on big +x is discarded)
      const float hnew = pre > 0.f ? pre : (__expf(pre) - 1.f);

      vrow[c * HH + lane] = hnew;  // vertical carry for next row
      hcur = hnew;

      // log_softmax(newH @ Wout + bout), pick logit of actual spin; off critical path.
      const float z0 = wave_sum64(hnew * wout0) + bout0;
      const float z1 = wave_sum64(hnew * wout1) + bout1;
      const float m = fmaxf(z0, z1);
      const float lse = m + __logf(__expf(z0 - m) + __expf(z1 - m));
      const unsigned spin = (curmask >> c) & 1u;
      float lp = (spin ? z1 : z0) - lse;
      lp = (lp == lp) ? lp : -35.0f;  // nan_to_num(nan=-35)
      total += lp;

      vj = vj_next;
      c = cn;
    }
    prevmask = curmask;
  }

  if (lane == 0) out[b] = 0.5f * total;  // LOGP_FACTOR * sum
}

extern "C" void kernel_launch(void* const* d_in, const int* in_sizes, int n_in,
                              void* d_out, int out_size, void* d_ws, size_t ws_size,
                              hipStream_t stream) {
  const int* x = (const int*)d_in[0];
  const float* Win = (const float*)d_in[1];
  const float* Wc = (const float*)d_in[2];
  const float* bc = (const float*)d_in[3];
  const float* Wout = (const float*)d_in[4];
  const float* bout = (const float*)d_in[5];
  float* out = (float*)d_out;
  // One 64-thread block (one wave) per batch sample.
  rnn2d_kernel<<<dim3(out_size), dim3(64), 0, stream>>>(x, Win, Wc, bc, Wout, bout, out);
}

// Round 4
// 443.333 us; speedup vs baseline: 1.0605x; 1.0573x over previous
//
#include <hip/hip_runtime.h>

#define LL 32
#define HH 64

// Broadcast lane `lane`'s value of v to all lanes via v_readlane (VALU, no LDS pipe).
__device__ __forceinline__ float bcast_lane(float v, int lane) {
  return __builtin_bit_cast(float, __builtin_amdgcn_readlane(__builtin_bit_cast(int, v), lane));
}

// Optimizer-opaque VGPR pin: forces `x` to live in a VGPR here and prevents
// the compiler from re-deriving it later (e.g. re-loading from global inside
// the hot loop). Without this the allocator kept the kernel at 44 VGPRs and
// re-loaded all 64 Wc values every step (~1005 cyc/step instead of ~400).
__device__ __forceinline__ void pin_vgpr(float& x) {
  asm volatile("" : "+v"(x));
}

// One DPP-shifted add step (bound_ctrl: out-of-range lanes contribute 0).
// CTRL must be a compile-time constant for __builtin_amdgcn_update_dpp.
template <int CTRL>
__device__ __forceinline__ float dpp_add_step(float x) {
  int y = __builtin_amdgcn_update_dpp(0, __builtin_bit_cast(int, x), CTRL, 0xf, 0xf, true);
  return x + __builtin_bit_cast(float, y);
}

// Full 64-lane sum, result broadcast as a wave-uniform value (via readlane 63).
// row_shr:1/2/4/8 accumulate within 16-lane rows; row_bcast15/31 merge rows.
__device__ __forceinline__ float wave_sum64(float x) {
  x = dpp_add_step<0x111>(x);  // row_shr:1
  x = dpp_add_step<0x112>(x);  // row_shr:2
  x = dpp_add_step<0x114>(x);  // row_shr:4
  x = dpp_add_step<0x118>(x);  // row_shr:8
  x = dpp_add_step<0x142>(x);  // row_bcast15
  x = dpp_add_step<0x143>(x);  // row_bcast31
  return __builtin_bit_cast(float, __builtin_amdgcn_readlane(__builtin_bit_cast(int, x), 63));
}

// One wave (64 lanes) per sample. Lane j owns hidden unit j.
// Wc column j in 64 VGPRs; vertical hidden carry prevH[c][j] in LDS (per-lane column).
// __launch_bounds__(64, 1): 1 wave/EU is the structural occupancy (1024 waves on
// 1024 SIMDs) — allow the register allocator the full VGPR file.
__global__ __launch_bounds__(64, 1) void rnn2d_kernel(
    const int* __restrict__ x, const float* __restrict__ Win,
    const float* __restrict__ Wc, const float* __restrict__ bc,
    const float* __restrict__ Wout, const float* __restrict__ bout,
    float* __restrict__ out) {
  const int lane = threadIdx.x;
  const int b = blockIdx.x;
  __shared__ float vrow[LL * HH];  // [column][hidden] — lane j only touches [.][j]

  // Weights resident in registers for the whole 1024-step recurrence.
  float wcol[HH];
#pragma unroll
  for (int i = 0; i < HH; ++i) wcol[i] = Wc[i * HH + lane];
  float win0 = Win[lane];            // Win[0][j]
  float win1 = Win[HH + lane];       // Win[1][j]
  float bcj = bc[lane];
  float wout0 = Wout[lane * 2 + 0];  // Wout[j][0]
  float wout1 = Wout[lane * 2 + 1];  // Wout[j][1]
  float bout0 = bout[0];
  float bout1 = bout[1];

  // Pin every preloaded weight into a VGPR so the hot loop cannot re-load them.
#pragma unroll
  for (int i = 0; i < HH; ++i) pin_vgpr(wcol[i]);
  pin_vgpr(win0); pin_vgpr(win1); pin_vgpr(bcj);
  pin_vgpr(wout0); pin_vgpr(wout1); pin_vgpr(bout0); pin_vgpr(bout1);

  // Row 0 sees zero vertical hidden carry.
#pragma unroll
  for (int c0 = 0; c0 < LL; ++c0) vrow[c0 * HH + lane] = 0.f;

  const int* xb = x + b * (LL * LL);
  unsigned prevmask = 0u;                         // previous row's spins (bit c = spin at column c)
  int spv = (lane < LL) ? xb[lane] : 0;           // prefetched row-0 spins
  float total = 0.f;

  for (int r = 0; r < LL; ++r) {
    const unsigned curmask =
        (unsigned)(__ballot(lane < LL && spv) & 0xffffffffull);
    if (r < LL - 1) spv = (lane < LL) ? xb[(r + 1) * LL + lane] : 0;  // prefetch next row

    const int odd = r & 1;
    const int d = odd ? -1 : 1;       // boustrophedon direction
    int c = odd ? (LL - 1) : 0;       // spatial column of scan step 0
    float hcur = 0.f;                 // horizontal hidden carry (zero at row start)
    float vj = vrow[c * HH + lane];   // vertical carry for step 0

    for (int k = 0; k < LL; ++k) {
      // Prefetch next step's vertical carry (address is ahead of this row's writes).
      const int cn = (c + d) & (LL - 1);
      const float vj_next = vrow[cn * HH + lane];

      const float hv = hcur + vj;  // (h + cV)[j], to be broadcast across lanes

      // newH[j] = sum_i hv[i] * Wc[i][j] — readlane broadcast + FMA, 4 accumulators.
      float a0 = 0.f, a1 = 0.f, a2 = 0.f, a3 = 0.f;
#pragma unroll
      for (int i = 0; i < HH; i += 4) {
        a0 = fmaf(bcast_lane(hv, i + 0), wcol[i + 0], a0);
        a1 = fmaf(bcast_lane(hv, i + 1), wcol[i + 1], a1);
        a2 = fmaf(bcast_lane(hv, i + 2), wcol[i + 2], a2);
        a3 = fmaf(bcast_lane(hv, i + 3), wcol[i + 3], a3);
      }

      // newR @ Win: one-hot row selects (spins are wave-uniform scalars from the bitmasks).
      float winc = 0.f;
      if (k > 0) {  // horizontal neighbor (previously visited site in this row)
        const unsigned sh = (curmask >> ((c - d) & 31)) & 1u;
        winc += sh ? win1 : win0;
      }
      if (r > 0) {  // vertical neighbor (same column, previous row)
        const unsigned sv = (prevmask >> c) & 1u;
        winc += sv ? win1 : win0;
      }

      const float pre = ((a0 + a1) + (a2 + a3)) + bcj + winc;
      // elu: x>0 ? x : exp(x)-1  (exp computed branchlessly; inf on big +x is discarded)
      const float hnew = pre > 0.f ? pre : (__expf(pre) - 1.f);

      vrow[c * HH + lane] = hnew;  // vertical carry for next row
      hcur = hnew;

      // log_softmax(newH @ Wout + bout), pick logit of actual spin; off critical path.
      const float z0 = wave_sum64(hnew * wout0) + bout0;
      const float z1 = wave_sum64(hnew * wout1) + bout1;
      const float m = fmaxf(z0, z1);
      const float lse = m + __logf(__expf(z0 - m) + __expf(z1 - m));
      const unsigned spin = (curmask >> c) & 1u;
      float lp = (spin ? z1 : z0) - lse;
      lp = (lp == lp) ? lp : -35.0f;  // nan_to_num(nan=-35)
      total += lp;

      vj = vj_next;
      c = cn;
    }
    prevmask = curmask;
  }

  if (lane == 0) out[b] = 0.5f * total;  // LOGP_FACTOR * sum
}

extern "C" void kernel_launch(void* const* d_in, const int* in_sizes, int n_in,
                              void* d_out, int out_size, void* d_ws, size_t ws_size,
                              hipStream_t stream) {
  const int* x = (const int*)d_in[0];
  const float* Win = (const float*)d_in[1];
  const float* Wc = (const float*)d_in[2];
  const float* bc = (const float*)d_in[3];
  const float* Wout = (const float*)d_in[4];
  const float* bout = (const float*)d_in[5];
  float* out = (float*)d_out;
  // One 64-thread block (one wave) per batch sample.
  rnn2d_kernel<<<dim3(out_size), dim3(64), 0, stream>>>(x, Win, Wc, bc, Wout, bout, out);
}